// Round 5
// baseline (1437.791 us; speedup 1.0000x reference)
//
#include <hip/hip_runtime.h>
#include <hip/hip_bf16.h>

typedef _Float16 f16;
typedef __attribute__((ext_vector_type(8))) _Float16 f16x8;
typedef __attribute__((ext_vector_type(4))) float f32x4;

// ---------------- global_load_lds helper (16B, wave-uniform LDS base + lane*16) ----
__device__ __forceinline__ void gload_lds16(const void* g, void* l) {
  __builtin_amdgcn_global_load_lds((const __attribute__((address_space(1))) void*)g,
                                   (__attribute__((address_space(3))) void*)l, 16, 0, 0);
}

// ---------------- weight transpose+cast: [81*CIN][COUT] f32 -> [COUT][81*CIN] f16 --
template<int CIN, int COUT>
__global__ __launch_bounds__(256) void wtrans_kernel(const float* __restrict__ src,
                                                     f16* __restrict__ dst) {
  constexpr int KT = 81 * CIN;
  __shared__ float tile[64][65];
  int k0 = blockIdx.x * 64;
  int n0 = blockIdx.y * 64;
  int t = threadIdx.x;
#pragma unroll
  for (int i = 0; i < 16; ++i) {
    int id = t + i * 256;
    int r = id >> 6, c = id & 63;
    tile[r][c] = src[(k0 + r) * COUT + n0 + c];
  }
  __syncthreads();
#pragma unroll
  for (int i = 0; i < 16; ++i) {
    int id = t + i * 256;
    int r = id >> 6, c = id & 63;  // r = n_local, c = k_local
    dst[(n0 + r) * KT + k0 + c] = (f16)tile[c][r];
  }
}

// ---------------- generic transpose+cast+pad: [K][N] f32 -> [NP][K] f16, zero rows n>=N
__global__ __launch_bounds__(256) void wtransg_kernel(const float* __restrict__ src,
                                                      f16* __restrict__ dst,
                                                      int K, int N, int NP) {
  __shared__ float tile[64][65];
  int k0 = blockIdx.x * 64;
  int n0 = blockIdx.y * 64;
  int t = threadIdx.x;
#pragma unroll
  for (int i = 0; i < 16; ++i) {
    int id = t + i * 256;
    int r = id >> 6, c = id & 63;  // r = k_local, c = n_local
    tile[r][c] = (n0 + c < N) ? src[(k0 + r) * N + n0 + c] : 0.f;
  }
  __syncthreads();
#pragma unroll
  for (int i = 0; i < 16; ++i) {
    int id = t + i * 256;
    int r = id >> 6, c = id & 63;  // r = n_local, c = k_local
    dst[(size_t)(n0 + r) * K + k0 + c] = (f16)tile[c][r];
  }
}

// ---------------- plain f32 -> f16 cast copy ----------------
__global__ __launch_bounds__(256) void cvtf16_kernel(const float* __restrict__ src,
                                                     f16* __restrict__ dst, int n) {
  int idx = blockIdx.x * 256 + threadIdx.x;
  if (idx < n) dst[idx] = (f16)src[idx];
}

// ---------------- conv1: 5x5, Cin=1, Cout=64, relu, f16 out ----------------
__global__ __launch_bounds__(256) void conv1_kernel(const float* __restrict__ x,
                                                    const float* __restrict__ kw,
                                                    const float* __restrict__ bias,
                                                    f16* __restrict__ out) {
  int idx = blockIdx.x * 256 + threadIdx.x;  // 256*36*36*64
  int co = idx & 63;
  int r = idx >> 6;
  int ow = r % 36; int r2 = r / 36; int oh = r2 % 36; int b = r2 / 36;
  float acc = bias[co];
  const float* xp = x + (b * 40 + oh) * 40 + ow;
#pragma unroll
  for (int dy = 0; dy < 5; ++dy)
#pragma unroll
    for (int dx = 0; dx < 5; ++dx)
      acc += xp[dy * 40 + dx] * kw[(dy * 5 + dx) * 64 + co];
  out[idx] = (f16)fmaxf(acc, 0.f);
}

// ---------------- im2col tap offset helpers ----------------
template<int CIN, int WIN>
__device__ __forceinline__ int tapA_off(int kt) {  // BK=64 chunks
  int tap, ci0;
  if (CIN == 64)       { tap = kt;      ci0 = 0; }
  else if (CIN == 128) { tap = kt >> 1; ci0 = (kt & 1) << 6; }
  else                 { tap = kt >> 2; ci0 = (kt & 3) << 6; }
  int dy = tap / 9, dx = tap - dy * 9;
  return (dy * WIN + dx) * CIN + ci0;
}

template<int CIN, int WIN>
__device__ __forceinline__ int tap32_off(int kt) {  // BK=32 chunks
  constexpr int CPT = CIN / 32;
  int tap = kt / CPT, ci0 = (kt % CPT) * 32;
  int dy = tap / 9, dx = tap - dy * 9;
  return (dy * WIN + dx) * CIN + ci0;
}

// ============ deep-pipelined 256x128 BK=32 implicit-GEMM conv (2 blocks/CU) =========
// 8 waves (4Mx2N), per-wave C = 64x64 (acc[4][4], 64 VGPR) -> total regs ~<128.
// LDS 48KB: A dbuf 2x16K [0,32K), B dbuf 2x8K [32K,48K). Rows 64B, swizzle:
//   granule slot gs holds data granule g = gs ^ ((row>>1)&3)  (2-way = free).
// Per tile T: top: bfr[4] hoist (B buf T&1).
//   P0: af(mf0,1); stage A(T+1) x2 -> buf (T+1)&1; bar; lgkm; 8 MFMA; bar.
//   P1: af(mf2,3); stage B(T+2) x1 -> buf (T+2)&1; vmcnt(1); bar; lgkm; 8 MFMA; bar.
// vmcnt(1): newest-1 = B(T+2) may fly; A(T+1) (issued P0) and B(T+1) (issued T-1 P1,
// older) enforced landed. Tail T+2>=NT -> vmcnt(0). B-overwrite of buf T&1 is safe:
// all waves' bfr are register-resident by P0's lgkmcnt(0), before P1 issues stores.
template<int HIN, int WIN, int CIN, int HOUT, int WOUT, int COUT, int STRIDE,
         bool RELU, bool OUTF16>
__global__ __launch_bounds__(512, 4) void convdp_kernel(const f16* __restrict__ in,
                                                        const f16* __restrict__ wt,
                                                        const float* __restrict__ bias,
                                                        f16* __restrict__ out16,
                                                        float* __restrict__ out32) {
  constexpr int KTOT = 81 * CIN;
  constexpr int NT = KTOT / 32;
  constexpr int NBLK = COUT / 128;
  __shared__ __align__(16) f16 lds[24576];  // 48 KiB
  const int bid = (int)blockIdx.x;
  const int mb = bid / NBLK, nb = bid % NBLK;
  const int t = threadIdx.x;
  const int wave = t >> 6, lane = t & 63;
  const int hi = lane >> 4, lo = lane & 15;
  const int wm = wave >> 1, wn = wave & 1;

  // staging source offsets (per-lane, constant across tiles up to tap offset)
  int Asrc[2], Bsrc;
  {
    int g = (lane & 3) ^ ((lane >> 3) & 3);  // inverse-swizzled data granule
#pragma unroll
    for (int c = 0; c < 2; ++c) {
      int r = c * 128 + wave * 16 + (lane >> 2);
      int m = mb * 256 + r;
      int b = m / (HOUT * WOUT);
      int rr = m - b * (HOUT * WOUT);
      int oh = rr / WOUT, ow = rr - oh * WOUT;
      Asrc[c] = ((b * HIN + oh * STRIDE) * WIN + ow * STRIDE) * CIN + g * 8;
    }
    int n = wave * 16 + (lane >> 2);
    Bsrc = (nb * 128 + n) * KTOT + g * 8;
  }
  const int gbx = (hi ^ ((lo >> 1) & 3)) << 4;  // fragment-read granule slot bytes
  const char* ldsc = (const char*)lds;
  char* ldsw = (char*)lds;

#define GA(c, tpo, bq) gload_lds16(in + Asrc[c] + (tpo),                            \
    (void*)(ldsw + (bq) * 16384 + ((c) * 512 + wave * 64) * 16))
#define GB(tile) gload_lds16(wt + Bsrc + (tile) * 32,                               \
    (void*)(ldsw + 32768 + ((tile) & 1) * 8192 + (wave * 64) * 16))

  // Prologue: A(0) x2, B(0), B(1). vmcnt(1) -> A(0),B(0) landed; B(1) may fly.
  {
    int tp0 = tap32_off<CIN, WIN>(0);
    GA(0, tp0, 0); GA(1, tp0, 0);
    GB(0); GB(1);
    asm volatile("s_waitcnt vmcnt(1)" ::: "memory");
    __builtin_amdgcn_s_barrier();
  }

  f32x4 acc[4][4] = {};

  for (int T = 0; T < NT; ++T) {
    const int q = T & 1;
    const char* Abq = ldsc + q * 16384 + (wm * 64 + lo) * 64;          // + mf*1024
    const char* Bbq = ldsc + 32768 + q * 8192 + (wn * 64 + lo) * 64;   // + nf*1024
    const int tpn = tap32_off<CIN, WIN>(T + 1);  // used only if T+1 < NT
    f16x8 bfr[4];
#pragma unroll
    for (int nf = 0; nf < 4; ++nf)
      bfr[nf] = *(const f16x8*)(Bbq + nf * 1024 + gbx);
    // ---- P0: mf 0,1 ----
    {
      f16x8 a0 = *(const f16x8*)(Abq + 0 * 1024 + gbx);
      f16x8 a1 = *(const f16x8*)(Abq + 1 * 1024 + gbx);
      if (T + 1 < NT) { GA(0, tpn, (T + 1) & 1); GA(1, tpn, (T + 1) & 1); }
      __builtin_amdgcn_s_barrier();
      asm volatile("s_waitcnt lgkmcnt(0)" ::: "memory");
      __builtin_amdgcn_sched_barrier(0);
      __builtin_amdgcn_s_setprio(1);
#pragma unroll
      for (int nf = 0; nf < 4; ++nf) {
        acc[0][nf] = __builtin_amdgcn_mfma_f32_16x16x32_f16(a0, bfr[nf], acc[0][nf], 0, 0, 0);
        acc[1][nf] = __builtin_amdgcn_mfma_f32_16x16x32_f16(a1, bfr[nf], acc[1][nf], 0, 0, 0);
      }
      __builtin_amdgcn_s_setprio(0);
      __builtin_amdgcn_s_barrier();
    }
    // ---- P1: mf 2,3 ----
    {
      f16x8 a2 = *(const f16x8*)(Abq + 2 * 1024 + gbx);
      f16x8 a3 = *(const f16x8*)(Abq + 3 * 1024 + gbx);
      if (T + 2 < NT) {
        GB(T + 2);
        asm volatile("s_waitcnt vmcnt(1)" ::: "memory");
      } else {
        asm volatile("s_waitcnt vmcnt(0)" ::: "memory");
      }
      __builtin_amdgcn_s_barrier();
      asm volatile("s_waitcnt lgkmcnt(0)" ::: "memory");
      __builtin_amdgcn_sched_barrier(0);
      __builtin_amdgcn_s_setprio(1);
#pragma unroll
      for (int nf = 0; nf < 4; ++nf) {
        acc[2][nf] = __builtin_amdgcn_mfma_f32_16x16x32_f16(a2, bfr[nf], acc[2][nf], 0, 0, 0);
        acc[3][nf] = __builtin_amdgcn_mfma_f32_16x16x32_f16(a3, bfr[nf], acc[3][nf], 0, 0, 0);
      }
      __builtin_amdgcn_s_setprio(0);
      __builtin_amdgcn_s_barrier();
    }
  }
#undef GA
#undef GB

  // Epilogue: C/D layout col = lane&15, row = (lane>>4)*4 + reg
#pragma unroll
  for (int mf = 0; mf < 4; ++mf) {
#pragma unroll
    for (int nf = 0; nf < 4; ++nf) {
      int m0 = mb * 256 + wm * 64 + mf * 16 + hi * 4;
      int n = nb * 128 + wn * 64 + nf * 16 + lo;
      float bval = bias[n];
#pragma unroll
      for (int r = 0; r < 4; ++r) {
        float v = acc[mf][nf][r] + bval;
        if (RELU) v = fmaxf(v, 0.f);
        int o = (m0 + r) * COUT + n;
        if (OUTF16) out16[o] = (f16)v; else out32[o] = v;
      }
    }
  }
}

// ---------------- implicit-GEMM conv via f16 MFMA (m97 structure, 128x128) --------
template<int HIN, int WIN, int CIN, int HOUT, int WOUT, int COUT, int STRIDE,
         bool RELU, bool OUTF16, int SPLIT, bool ADDBIAS>
__global__ __launch_bounds__(256) void conv_mfma_kernel(const f16* __restrict__ in,
                                                        const f16* __restrict__ wt,
                                                        const float* __restrict__ bias,
                                                        f16* __restrict__ out16,
                                                        float* __restrict__ out32) {
  constexpr int KTOT = 81 * CIN;
  constexpr int NBLK = COUT / 128;
  constexpr int MTOT = 256 * HOUT * WOUT;
  constexpr int MBNB = (MTOT / 128) * NBLK;
  constexpr int NKT = (KTOT / 64) / SPLIT;
  __shared__ __align__(16) f16 lds[16384];
  int bidx = (int)blockIdx.x;
  int ks = 0;
  if (SPLIT > 1) { ks = bidx / MBNB; bidx -= ks * MBNB; }
  const int mb = bidx / NBLK;
  const int nb = bidx % NBLK;
  const int t = threadIdx.x;
  const int wave = t >> 6, lane = t & 63;
  const int hi = lane >> 4, lo = lane & 15;
  const bool isA = wave < 2;
  const int slot0 = wave << 9;

  int baseoff[8];
#pragma unroll
  for (int it = 0; it < 8; ++it) {
    int s = slot0 + it * 64 + lane;
    if (isA) {
      int row = s >> 3;
      int g = (s & 7) ^ (row & 7);
      int mg = mb * 128 + row;
      int b = mg / (HOUT * WOUT);
      int rr = mg - b * (HOUT * WOUT);
      int oh = rr / WOUT;
      int ow = rr - oh * WOUT;
      baseoff[it] = ((b * HIN + oh * STRIDE) * WIN + ow * STRIDE) * CIN + g * 8;
    } else {
      int sl = s - 1024;
      int row = sl >> 3;
      int g = (sl & 7) ^ (row & 7);
      baseoff[it] = (nb * 128 + row) * KTOT + g * 8;
    }
  }
  const f16* gsrc = isA ? in : wt;

  int aQ[4], bQ[4];
  const int wm = wave >> 1, wn = wave & 1;
#pragma unroll
  for (int f = 0; f < 4; ++f) {
    int arow = wm * 64 + f * 16 + lo;
    aQ[f] = (arow * 128) ^ ((arow & 7) << 4);
    int brow = wn * 64 + f * 16 + lo;
    bQ[f] = 16384 + ((brow * 128) ^ ((brow & 7) << 4));
  }

  f32x4 acc[4][4] = {};
  const char* ldsc = (const char*)lds;

  const int kt0 = ks * NKT;
  for (int kt = kt0; kt < kt0 + NKT; ++kt) {
    int tapoff;
    if (isA) tapoff = tapA_off<CIN, WIN>(kt);
    else     tapoff = kt << 6;
    __syncthreads();
#pragma unroll
    for (int it = 0; it < 8; ++it)
      gload_lds16(gsrc + baseoff[it] + tapoff,
                  (void*)((char*)lds + ((slot0 + it * 64) << 4)));
    __syncthreads();
#pragma unroll
    for (int sub = 0; sub < 2; ++sub) {
      const int gx = (sub * 4 + hi) << 4;
      f16x8 av[4], bv[4];
#pragma unroll
      for (int f = 0; f < 4; ++f) av[f] = *(const f16x8*)(ldsc + (aQ[f] ^ gx));
#pragma unroll
      for (int f = 0; f < 4; ++f) bv[f] = *(const f16x8*)(ldsc + (bQ[f] ^ gx));
#pragma unroll
      for (int mf = 0; mf < 4; ++mf)
#pragma unroll
        for (int nf = 0; nf < 4; ++nf)
          acc[mf][nf] = __builtin_amdgcn_mfma_f32_16x16x32_f16(av[mf], bv[nf],
                                                               acc[mf][nf], 0, 0, 0);
    }
  }

  float* o32 = out32 + (size_t)ks * MTOT * COUT;
#pragma unroll
  for (int mf = 0; mf < 4; ++mf) {
#pragma unroll
    for (int nf = 0; nf < 4; ++nf) {
      int m0 = mb * 128 + wm * 64 + mf * 16 + hi * 4;
      int n = nb * 128 + wn * 64 + nf * 16 + lo;
      float bval = ADDBIAS ? bias[n] : 0.f;
#pragma unroll
      for (int r = 0; r < 4; ++r) {
        float v = acc[mf][nf][r] + bval;
        if (RELU) v = fmaxf(v, 0.f);
        int o = (m0 + r) * COUT + n;
        if (OUTF16) out16[o] = (f16)v; else o32[o] = v;
      }
    }
  }
}

// ---------------- prim K-split reduction: p = bias + sum_s partial[s] ----------------
__global__ __launch_bounds__(256) void prim_reduce_kernel(const float* __restrict__ part,
                                                          const float* __restrict__ bias,
                                                          float* __restrict__ p) {
  int idx = blockIdx.x * 256 + threadIdx.x;  // 9216*256
  int n = idx & 255;
  float a = bias[n];
#pragma unroll
  for (int s = 0; s < 4; ++s) a += part[s * 2359296 + idx];
  p[idx] = a;
}

// ---------------- dense GEMM via f16 MFMA: A[256][K] x Bw[NP][K]^T (+bias, act) -----
template<int K, int NP, int NOUT, int ACT>
__global__ __launch_bounds__(256) void gemm_mfma_kernel(const f16* __restrict__ A,
                                                        const f16* __restrict__ Bw,
                                                        const float* __restrict__ bias,
                                                        f16* __restrict__ out16,
                                                        float* __restrict__ out32) {
  constexpr int NBLK = NP / 128;
  __shared__ __align__(16) f16 lds[16384];
  const int mb = (int)blockIdx.x / NBLK;
  const int nb = (int)blockIdx.x % NBLK;
  const int t = threadIdx.x;
  const int wave = t >> 6, lane = t & 63;
  const int hi = lane >> 4, lo = lane & 15;
  const bool isA = wave < 2;
  const int slot0 = wave << 9;

  int baseoff[8];
#pragma unroll
  for (int it = 0; it < 8; ++it) {
    int s = slot0 + it * 64 + lane;
    if (isA) {
      int row = s >> 3;
      int g = (s & 7) ^ (row & 7);
      baseoff[it] = (mb * 128 + row) * K + g * 8;
    } else {
      int sl = s - 1024;
      int row = sl >> 3;
      int g = (sl & 7) ^ (row & 7);
      baseoff[it] = (nb * 128 + row) * K + g * 8;
    }
  }
  const f16* gsrc = isA ? A : Bw;

  int aQ[4], bQ[4];
  const int wm = wave >> 1, wn = wave & 1;
#pragma unroll
  for (int f = 0; f < 4; ++f) {
    int arow = wm * 64 + f * 16 + lo;
    aQ[f] = (arow * 128) ^ ((arow & 7) << 4);
    int brow = wn * 64 + f * 16 + lo;
    bQ[f] = 16384 + ((brow * 128) ^ ((brow & 7) << 4));
  }

  f32x4 acc[4][4] = {};
  const char* ldsc = (const char*)lds;

  for (int kt = 0; kt < K / 64; ++kt) {
    int tapoff = kt << 6;
    __syncthreads();
#pragma unroll
    for (int it = 0; it < 8; ++it)
      gload_lds16(gsrc + baseoff[it] + tapoff,
                  (void*)((char*)lds + ((slot0 + it * 64) << 4)));
    __syncthreads();
#pragma unroll
    for (int sub = 0; sub < 2; ++sub) {
      const int gx = (sub * 4 + hi) << 4;
      f16x8 av[4], bv[4];
#pragma unroll
      for (int f = 0; f < 4; ++f) av[f] = *(const f16x8*)(ldsc + (aQ[f] ^ gx));
#pragma unroll
      for (int f = 0; f < 4; ++f) bv[f] = *(const f16x8*)(ldsc + (bQ[f] ^ gx));
#pragma unroll
      for (int mf = 0; mf < 4; ++mf)
#pragma unroll
        for (int nf = 0; nf < 4; ++nf)
          acc[mf][nf] = __builtin_amdgcn_mfma_f32_16x16x32_f16(av[mf], bv[nf],
                                                               acc[mf][nf], 0, 0, 0);
    }
  }

#pragma unroll
  for (int mf = 0; mf < 4; ++mf) {
#pragma unroll
    for (int nf = 0; nf < 4; ++nf) {
      int m0 = mb * 128 + wm * 64 + mf * 16 + hi * 4;
      int n = nb * 128 + wn * 64 + nf * 16 + lo;
      if (n < NOUT) {
        float bval = bias[n];
#pragma unroll
        for (int r = 0; r < 4; ++r) {
          float v = acc[mf][nf][r] + bval;
          if (ACT == 0) out16[(m0 + r) * NOUT + n] = (f16)fmaxf(v, 0.f);
          else          out32[(m0 + r) * NOUT + n] = 1.f / (1.f + expf(-v));
        }
      }
    }
  }
}

// ---------------- u_hat[b,i,j,k] = sum_v w[i,j,k,v]*u[b,i,v]  (f16 out) ----------
__global__ __launch_bounds__(256) void uhat_kernel(const f16* __restrict__ wf,
                                                   const float* __restrict__ u,
                                                   f16* __restrict__ uh) {
  int idx = blockIdx.x * 256 + threadIdx.x;  // 256*1152*160
  int bi = idx / 160;
  int jk = idx - bi * 160;
  int i = bi % 1152;
  const f16x8 wv = *(const f16x8*)(wf + (i * 160 + jk) * 8);
  const float4* uv = (const float4*)(u + bi * 8);
  float4 u0 = uv[0], u1 = uv[1];
  float acc = (float)wv[0] * u0.x + (float)wv[1] * u0.y + (float)wv[2] * u0.z +
              (float)wv[3] * u0.w + (float)wv[4] * u1.x + (float)wv[5] * u1.y +
              (float)wv[6] * u1.z + (float)wv[7] * u1.w;
  uh[idx] = (f16)acc;
}

// ---------------- routing pass A: c=softmax(b), s=sum_i c*u_hat, v=squash(s) ------
template<bool FIRST>
__global__ __launch_bounds__(512) void routeA_kernel(const f16* __restrict__ uh,
                                                     const float* __restrict__ blog,
                                                     float* __restrict__ vbuf,
                                                     float* __restrict__ vout) {
  __shared__ float csm[1152 * 10];
  __shared__ float sp[320];
  int b = blockIdx.x, t = threadIdx.x;
  for (int i = t; i < 1152; i += 512) {
    if (FIRST) {
#pragma unroll
      for (int j = 0; j < 10; ++j) csm[i * 10 + j] = 0.1f;
    } else {
      float l[10];
#pragma unroll
      for (int j = 0; j < 10; ++j) l[j] = blog[(b * 1152 + i) * 10 + j];
      float mx = l[0];
#pragma unroll
      for (int j = 1; j < 10; ++j) mx = fmaxf(mx, l[j]);
      float sum = 0.f;
#pragma unroll
      for (int j = 0; j < 10; ++j) { l[j] = expf(l[j] - mx); sum += l[j]; }
      float inv = 1.f / sum;
#pragma unroll
      for (int j = 0; j < 10; ++j) csm[i * 10 + j] = l[j] * inv;
    }
  }
  __syncthreads();
  if (t < 320) {
    int half = (t >= 160) ? 1 : 0;
    int jk = t - half * 160;
    int j = jk >> 4;
    const f16* up = uh + b * 184320 + jk;
    int i0 = half * 576;
    float s = 0.f;
    for (int i = i0; i < i0 + 576; i += 8) {
#pragma unroll
      for (int u = 0; u < 8; ++u)
        s += csm[(i + u) * 10 + j] * (float)up[(i + u) * 160];
    }
    sp[t] = s;
  }
  __syncthreads();
  if (t < 160) {
    float s = sp[t] + sp[t + 160];
    float ss = s * s;
    ss += __shfl_xor(ss, 1, 16);
    ss += __shfl_xor(ss, 2, 16);
    ss += __shfl_xor(ss, 4, 16);
    ss += __shfl_xor(ss, 8, 16);
    float n = sqrtf(ss);
    float f = ss / ((1.f + ss) * (n + 1e-7f));
    float v = f * s;
    vbuf[b * 160 + t] = v;
    vout[b * 160 + t] = v;
  }
}

// ---------------- routing pass B: b_logit (+)= sum_k u_hat*v ----------------
template<bool ACCUM>
__global__ __launch_bounds__(256) void routeB_kernel(const f16* __restrict__ uh,
                                                     const float* __restrict__ vbuf,
                                                     float* __restrict__ blog) {
  int idx = blockIdx.x * 256 + threadIdx.x;  // 256*1152
  int b = idx / 1152;
  float agr[10] = {};
  const f16x8* row = (const f16x8*)(uh + idx * 160);
  const float* vb = vbuf + b * 160;
#pragma unroll
  for (int c8 = 0; c8 < 20; ++c8) {
    f16x8 ch = row[c8];
#pragma unroll
    for (int e = 0; e < 8; ++e) {
      int jk = c8 * 8 + e;
      agr[jk >> 4] += (float)ch[e] * vb[jk];
    }
  }
#pragma unroll
  for (int j = 0; j < 10; ++j) {
    int o = idx * 10 + j;
    blog[o] = (ACCUM ? blog[o] : 0.f) + agr[j];
  }
}

// ---------------- mask by label + dense1 (160->1024, relu, f16 out) ----------------
__global__ __launch_bounds__(256) void maskd1_kernel(const float* __restrict__ vbuf,
                                                     const int* __restrict__ y,
                                                     const float* __restrict__ w1,
                                                     const float* __restrict__ b1,
                                                     f16* __restrict__ r1) {
  int idx = blockIdx.x * 256 + threadIdx.x;  // 256*1024
  int o = idx & 1023;
  int b = idx >> 10;
  int yb = y[b];
  const float* vv = vbuf + b * 160 + yb * 16;
  float acc = b1[o];
#pragma unroll
  for (int k = 0; k < 16; ++k) acc += vv[k] * w1[(yb * 16 + k) * 1024 + o];
  r1[idx] = (f16)fmaxf(acc, 0.f);
}

// ---------------- launch ----------------
extern "C" void kernel_launch(void* const* d_in, const int* in_sizes, int n_in,
                              void* d_out, int out_size, void* d_ws, size_t ws_size,
                              hipStream_t stream) {
  const float* x       = (const float*)d_in[0];
  const int*   y       = (const int*)d_in[1];
  const float* conv1_k = (const float*)d_in[2];
  const float* conv1_b = (const float*)d_in[3];
  const float* conv2_k = (const float*)d_in[4];
  const float* conv2_b = (const float*)d_in[5];
  const float* conv3_k = (const float*)d_in[6];
  const float* conv3_b = (const float*)d_in[7];
  const float* prim_k  = (const float*)d_in[8];
  const float* prim_b  = (const float*)d_in[9];
  const float* w_route = (const float*)d_in[10];
  const float* d1_w = (const float*)d_in[11];
  const float* d1_b = (const float*)d_in[12];
  const float* d2_w = (const float*)d_in[13];
  const float* d2_b = (const float*)d_in[14];
  const float* d3_w = (const float*)d_in[15];
  const float* d3_b = (const float*)d_in[16];

  // workspace layout (bytes), total 191,021,056 (same as R1-R4 -> proven fits):
  char* ws = (char*)d_ws;
  f16*   h1   = (f16*)(ws + 0);
  f16*   h2   = (f16*)(ws + 42467328);
  f16*   h3   = (f16*)(ws + 93847552);
  float* part = (float*)(ws + 0);                    // 4 x 9,437,184 B = 37,748,736
  f16*   uhat = (f16*)(ws + 0);                      // 94,371,840 B (alias)
  float* p    = (float*)(ws + 146276352);            //  9,437,184 B
  float* blog = (float*)(ws + 155713536);            // 11,796,480 B
  f16*   wd2  = (f16*)(ws + 155713536);              //  4,194,304 B (alias, post-routing)
  f16*   wd3  = (f16*)(ws + 159907840);              //  6,815,744 B (alias, post-routing)
  float* vbuf = (float*)(ws + 167510016);            //    163,840 B
  f16*   r1h  = (f16*)(ws + 167673856);              //    524,288 B
  f16*   r2h  = (f16*)(ws + 168198144);              //  1,048,576 B
  f16*   wt2  = (f16*)(ws + 170819584);              //  1,327,104 B
  f16*   wt3  = (f16*)(ws + 172146688);              //  5,308,416 B
  f16*   wtp  = (f16*)(ws + 177455104);              // 10,616,832 B
  f16*   wf16 = (f16*)(ws + 188071936);              //  2,949,120 B -> 191,021,056

  float* vout  = (float*)d_out;            // [256,1,10,16] = 40960 f32
  float* recon = (float*)d_out + 40960;    // [256,1600]

  // weight prep
  wtrans_kernel<64, 128><<<dim3(81, 2), 256, 0, stream>>>(conv2_k, wt2);
  wtrans_kernel<128, 256><<<dim3(162, 4), 256, 0, stream>>>(conv3_k, wt3);
  wtrans_kernel<256, 256><<<dim3(324, 4), 256, 0, stream>>>(prim_k, wtp);
  cvtf16_kernel<<<5760, 256, 0, stream>>>(w_route, wf16, 1474560);

  // conv stack
  conv1_kernel<<<82944, 256, 0, stream>>>(x, conv1_k, conv1_b, h1);
  // conv2: deep-pipelined 256x128 BK=32, 2 blocks/CU (784 blocks)
  convdp_kernel<36, 36, 64, 28, 28, 128, 1, true, true>
      <<<784, 512, 0, stream>>>(h1, wt2, conv2_b, h2, nullptr);
  // conv3: deep-pipelined 256x128 BK=32, 2 blocks/CU (800 blocks)
  convdp_kernel<28, 28, 128, 20, 20, 256, 1, true, true>
      <<<800, 512, 0, stream>>>(h2, wt3, conv3_b, h3, nullptr);
  // prim caps: K-split x4 (m97 structure), partials + reduce
  conv_mfma_kernel<20, 20, 256, 6, 6, 256, 2, false, false, 4, false>
      <<<576, 256, 0, stream>>>(h3, wtp, prim_b, nullptr, part);
  prim_reduce_kernel<<<9216, 256, 0, stream>>>(part, prim_b, p);

  // capsule predictions + dynamic routing (R=3; last agreement is dead -> skipped)
  uhat_kernel<<<184320, 256, 0, stream>>>(wf16, p, uhat);
  routeA_kernel<true><<<256, 512, 0, stream>>>(uhat, blog, vbuf, vout);
  routeB_kernel<false><<<1152, 256, 0, stream>>>(uhat, vbuf, blog);
  routeA_kernel<false><<<256, 512, 0, stream>>>(uhat, blog, vbuf, vout);
  routeB_kernel<true><<<1152, 256, 0, stream>>>(uhat, vbuf, blog);
  routeA_kernel<false><<<256, 512, 0, stream>>>(uhat, blog, vbuf, vout);

  // masked reconstruction (dense weights -> f16 [N][K] into dead blog region)
  wtransg_kernel<<<dim3(16, 32), 256, 0, stream>>>(d2_w, wd2, 1024, 2048, 2048);
  wtransg_kernel<<<dim3(32, 26), 256, 0, stream>>>(d3_w, wd3, 2048, 1600, 1664);
  maskd1_kernel<<<1024, 256, 0, stream>>>(vbuf, y, d1_w, d1_b, r1h);
  gemm_mfma_kernel<1024, 2048, 2048, 0><<<32, 256, 0, stream>>>(r1h, wd2, d2_b, r2h, nullptr);
  gemm_mfma_kernel<2048, 1664, 1600, 1><<<26, 256, 0, stream>>>(r2h, wd3, d3_b, nullptr, recon);
}

// Round 6
// 1396.979 us; speedup vs baseline: 1.0292x; 1.0292x over previous
//
#include <hip/hip_runtime.h>
#include <hip/hip_bf16.h>

typedef _Float16 f16;
typedef __attribute__((ext_vector_type(8))) _Float16 f16x8;
typedef __attribute__((ext_vector_type(4))) float f32x4;

// ---------------- global_load_lds helper (16B, wave-uniform LDS base + lane*16) ----
__device__ __forceinline__ void gload_lds16(const void* g, void* l) {
  __builtin_amdgcn_global_load_lds((const __attribute__((address_space(1))) void*)g,
                                   (__attribute__((address_space(3))) void*)l, 16, 0, 0);
}

// ---------------- weight transpose+cast: [81*CIN][COUT] f32 -> [COUT][81*CIN] f16 --
template<int CIN, int COUT>
__global__ __launch_bounds__(256) void wtrans_kernel(const float* __restrict__ src,
                                                     f16* __restrict__ dst) {
  constexpr int KT = 81 * CIN;
  __shared__ float tile[64][65];
  int k0 = blockIdx.x * 64;
  int n0 = blockIdx.y * 64;
  int t = threadIdx.x;
#pragma unroll
  for (int i = 0; i < 16; ++i) {
    int id = t + i * 256;
    int r = id >> 6, c = id & 63;
    tile[r][c] = src[(k0 + r) * COUT + n0 + c];
  }
  __syncthreads();
#pragma unroll
  for (int i = 0; i < 16; ++i) {
    int id = t + i * 256;
    int r = id >> 6, c = id & 63;  // r = n_local, c = k_local
    dst[(n0 + r) * KT + k0 + c] = (f16)tile[c][r];
  }
}

// ---------------- generic transpose+cast+pad: [K][N] f32 -> [NP][K] f16, zero rows n>=N
__global__ __launch_bounds__(256) void wtransg_kernel(const float* __restrict__ src,
                                                      f16* __restrict__ dst,
                                                      int K, int N, int NP) {
  __shared__ float tile[64][65];
  int k0 = blockIdx.x * 64;
  int n0 = blockIdx.y * 64;
  int t = threadIdx.x;
#pragma unroll
  for (int i = 0; i < 16; ++i) {
    int id = t + i * 256;
    int r = id >> 6, c = id & 63;  // r = k_local, c = n_local
    tile[r][c] = (n0 + c < N) ? src[(k0 + r) * N + n0 + c] : 0.f;
  }
  __syncthreads();
#pragma unroll
  for (int i = 0; i < 16; ++i) {
    int id = t + i * 256;
    int r = id >> 6, c = id & 63;  // r = n_local, c = k_local
    dst[(size_t)(n0 + r) * K + k0 + c] = (f16)tile[c][r];
  }
}

// ---------------- plain f32 -> f16 cast copy ----------------
__global__ __launch_bounds__(256) void cvtf16_kernel(const float* __restrict__ src,
                                                     f16* __restrict__ dst, int n) {
  int idx = blockIdx.x * 256 + threadIdx.x;
  if (idx < n) dst[idx] = (f16)src[idx];
}

// ---------------- conv1: 5x5, Cin=1, Cout=64, relu, f16 out (8 couts/thread) -------
__global__ __launch_bounds__(256) void conv1_kernel(const float* __restrict__ x,
                                                    const float* __restrict__ kw,
                                                    const float* __restrict__ bias,
                                                    f16* __restrict__ out) {
  int idx = blockIdx.x * 256 + threadIdx.x;  // 256*36*36*8 threads
  int g = idx & 7;
  int co0 = g * 8;
  int r = idx >> 3;
  int ow = r % 36; int r2 = r / 36; int oh = r2 % 36; int b = r2 / 36;
  float acc[8];
#pragma unroll
  for (int j = 0; j < 8; ++j) acc[j] = bias[co0 + j];
  const float* xp = x + (b * 40 + oh) * 40 + ow;
#pragma unroll
  for (int dy = 0; dy < 5; ++dy)
#pragma unroll
    for (int dx = 0; dx < 5; ++dx) {
      float xv = xp[dy * 40 + dx];
      const float* kp = kw + (dy * 5 + dx) * 64 + co0;
#pragma unroll
      for (int j = 0; j < 8; ++j) acc[j] += xv * kp[j];
    }
  f16x8 o;
#pragma unroll
  for (int j = 0; j < 8; ++j) o[j] = (f16)fmaxf(acc[j], 0.f);
  *(f16x8*)(out + r * 64 + co0) = o;
}

// ---------------- im2col tap offset helper (BK=64 chunks) ----------------
template<int CIN, int WIN>
__device__ __forceinline__ int tapA_off(int kt) {
  int tap, ci0;
  if (CIN == 64)       { tap = kt;      ci0 = 0; }
  else if (CIN == 128) { tap = kt >> 1; ci0 = (kt & 1) << 6; }
  else                 { tap = kt >> 2; ci0 = (kt & 3) << 6; }
  int dy = tap / 9, dx = tap - dy * 9;
  return (dy * WIN + dx) * CIN + ci0;
}

// ============ 8-phase 256x256 implicit-GEMM conv (HK-template port) =================
// BM=BN=256, BK=64, 8 waves (2Mx4N), per-wave C = 128x64 (acc[8][4] f32x4).
// LDS 128KB: A bufs [0,64K), B bufs [64K,128K). XOR-swizzle byte^=((row&7)<<4).
// Tail-smoothing: grid = FULLB + 2*TAILB. bids < FULLB compute full K and write
// h3 directly; the rest compute one K-half of a tail tile and write raw f16
// partials (reduced by tailred_kernel). Buffer parity is absolute (tile&1), so
// the pipeline is unchanged; staging predicates use [kt0, kt1).
template<int HIN, int WIN, int CIN, int HOUT, int WOUT, int COUT, int STRIDE,
         bool RELU, bool OUTF16, int FULLB, int TAILB>
__global__ __launch_bounds__(512, 2) void conv8p_kernel(const f16* __restrict__ in,
                                                        const f16* __restrict__ wt,
                                                        const float* __restrict__ bias,
                                                        f16* __restrict__ out16,
                                                        float* __restrict__ out32,
                                                        f16* __restrict__ tpart) {
  static_assert(COUT == 256, "BN=256 template requires COUT==256");
  constexpr int KTOT = 81 * CIN;
  constexpr int NT = KTOT / 64;
  constexpr int HNT = NT / 2;
  __shared__ __align__(16) f16 lds[65536];  // 128 KiB
  const int bid = (int)blockIdx.x;
  int mb, kt0, kt1, pbase = 0;
  bool tail = false;
  if (TAILB == 0 || bid < FULLB) {
    mb = bid; kt0 = 0; kt1 = NT;
  } else {
    tail = true;
    int idx = bid - FULLB;
    int half = idx / TAILB;
    int loc = idx - half * TAILB;
    mb = FULLB + loc;
    kt0 = half * HNT; kt1 = kt0 + HNT;
    pbase = (half * TAILB + loc) * 65536;
  }
  const int t = threadIdx.x;
  const int wave = t >> 6, lane = t & 63;
  const int hi = lane >> 4, lo = lane & 15;
  const int wm = wave >> 2, wn = wave & 3;

  int Aoff[4], Boff[4];
  {
    int g = (lane & 7) ^ ((lane >> 3) & 7);  // inverse swizzle granule
#pragma unroll
    for (int rbi = 0; rbi < 4; ++rbi) {
      int r = rbi * 64 + 8 * wave + (lane >> 3);
      int m = mb * 256 + r;
      int b = m / (HOUT * WOUT);
      int rr = m - b * (HOUT * WOUT);
      int oh = rr / WOUT, ow = rr - oh * WOUT;
      Aoff[rbi] = ((b * HIN + oh * STRIDE) * WIN + ow * STRIDE) * CIN + g * 8;
      Boff[rbi] = r * KTOT + g * 8;
    }
  }
  const int gb0 = (hi ^ (lo & 7)) << 4;
  const int gb1 = ((4 + hi) ^ (lo & 7)) << 4;

  const char* ldsc = (const char*)lds;
  char* ldsw = (char*)lds;

#define GA(rbi, tpo, bq) gload_lds16(in + Aoff[rbi] + (tpo),                        \
    (void*)(ldsw + (bq) * 32768 + ((rbi) * 64 + 8 * wave) * 128))
#define GB(rbi, tile) gload_lds16(wt + Boff[rbi] + ((tile) << 6),                   \
    (void*)(ldsw + 65536 + ((tile) & 1) * 32768 + ((rbi) * 64 + 8 * wave) * 128))

  // Prologue: tile kt0 full (A then B), tile kt0+1 B. vmcnt(4) -> tile kt0 landed.
  {
    int tp0 = tapA_off<CIN, WIN>(kt0);
    int bq = kt0 & 1;
    GA(0, tp0, bq); GA(2, tp0, bq); GA(1, tp0, bq); GA(3, tp0, bq);
    GB(0, kt0); GB(1, kt0); GB(2, kt0); GB(3, kt0);
    GB(0, kt0 + 1); GB(1, kt0 + 1); GB(2, kt0 + 1); GB(3, kt0 + 1);
    asm volatile("s_waitcnt vmcnt(4)" ::: "memory");
    __builtin_amdgcn_s_barrier();
  }

  f32x4 acc[8][4] = {};

#define DO_PHASE(Q, STAGE)                                                          \
  {                                                                                 \
    f16x8 af[2][2];                                                                 \
    _Pragma("unroll")                                                               \
    for (int mf = 0; mf < 2; ++mf) {                                                \
      af[mf][0] = *(const f16x8*)(Ab + ((Q) * 2 + mf) * 2048 + gb0);                \
      af[mf][1] = *(const f16x8*)(Ab + ((Q) * 2 + mf) * 2048 + gb1);                \
    }                                                                               \
    STAGE;                                                                          \
    __builtin_amdgcn_s_barrier();                                                   \
    asm volatile("s_waitcnt lgkmcnt(0)" ::: "memory");                              \
    __builtin_amdgcn_sched_barrier(0);                                              \
    __builtin_amdgcn_s_setprio(1);                                                  \
    _Pragma("unroll")                                                               \
    for (int sb = 0; sb < 2; ++sb)                                                  \
      _Pragma("unroll")                                                             \
      for (int mf = 0; mf < 2; ++mf)                                                \
        _Pragma("unroll")                                                           \
        for (int nf = 0; nf < 4; ++nf)                                              \
          acc[(Q) * 2 + mf][nf] = __builtin_amdgcn_mfma_f32_16x16x32_f16(           \
              af[mf][sb], bfr[nf][sb], acc[(Q) * 2 + mf][nf], 0, 0, 0);             \
    __builtin_amdgcn_s_setprio(0);                                                  \
    __builtin_amdgcn_s_barrier();                                                   \
  }

  for (int T = kt0; T < kt1; ++T) {
    const int q = T & 1;
    const char* Ab = ldsc + q * 32768 + wm * 16384 + lo * 128;
    const char* Bb = ldsc + 65536 + q * 32768 + wn * 8192 + lo * 128;
    const int tpn = tapA_off<CIN, WIN>(T + 1);  // used only if T+1 < kt1
    f16x8 bfr[4][2];
#pragma unroll
    for (int nf = 0; nf < 4; ++nf) {
      bfr[nf][0] = *(const f16x8*)(Bb + nf * 2048 + gb0);
      bfr[nf][1] = *(const f16x8*)(Bb + nf * 2048 + gb1);
    }
    DO_PHASE(0, if (T + 1 < kt1) { GA(0, tpn, (T + 1) & 1); GA(2, tpn, (T + 1) & 1); })
    DO_PHASE(1, if (T + 1 < kt1) { GA(1, tpn, (T + 1) & 1); GA(3, tpn, (T + 1) & 1); })
    DO_PHASE(2, if (T + 2 < kt1) { GB(0, T + 2); GB(1, T + 2); })
    DO_PHASE(3,
      if (T + 2 < kt1) {
        GB(2, T + 2); GB(3, T + 2);
        asm volatile("s_waitcnt vmcnt(4)" ::: "memory");
      } else {
        asm volatile("s_waitcnt vmcnt(0)" ::: "memory");
      })
  }
#undef DO_PHASE
#undef GA
#undef GB

  // Epilogue: C/D layout col = lane&15, row = (lane>>4)*4 + reg
  if (!tail) {
#pragma unroll
    for (int mfr = 0; mfr < 8; ++mfr) {
#pragma unroll
      for (int nf = 0; nf < 4; ++nf) {
        int m0 = mb * 256 + wm * 128 + mfr * 16 + hi * 4;
        int n = wn * 64 + nf * 16 + lo;
        float bval = bias[n];
#pragma unroll
        for (int r = 0; r < 4; ++r) {
          float v = acc[mfr][nf][r] + bval;
          if (RELU) v = fmaxf(v, 0.f);
          int o = (m0 + r) * COUT + n;
          if (OUTF16) out16[o] = (f16)v; else out32[o] = v;
        }
      }
    }
  } else {
#pragma unroll
    for (int mfr = 0; mfr < 8; ++mfr) {
#pragma unroll
      for (int nf = 0; nf < 4; ++nf) {
        int rowloc = wm * 128 + mfr * 16 + hi * 4;
        int n = wn * 64 + nf * 16 + lo;
#pragma unroll
        for (int r = 0; r < 4; ++r)
          tpart[pbase + (rowloc + r) * 256 + n] = (f16)acc[mfr][nf][r];
      }
    }
  }
}

// ---------------- tail reduce: h3[tail rows] = relu(p0 + p1 + bias), x8 vec --------
__global__ __launch_bounds__(256) void tailred_kernel(const f16* __restrict__ tp,
                                                      const float* __restrict__ bias,
                                                      f16* __restrict__ h3) {
  int idx = blockIdx.x * 256 + threadIdx.x;  // 4608 blocks: 9,437,184 elems / 8
  int e0 = idx * 8;
  int n0 = e0 & 255;
  f16x8 a = *(const f16x8*)(tp + e0);
  f16x8 b = *(const f16x8*)(tp + 9437184 + e0);
  f16x8 o;
#pragma unroll
  for (int j = 0; j < 8; ++j) {
    float v = (float)a[j] + (float)b[j] + bias[n0 + j];
    o[j] = (f16)fmaxf(v, 0.f);
  }
  *(f16x8*)(h3 + 16777216 + e0) = o;  // tail tiles start at m = 256*256
}

// ---------------- implicit-GEMM conv via f16 MFMA (m97 structure, 128x128) --------
template<int HIN, int WIN, int CIN, int HOUT, int WOUT, int COUT, int STRIDE,
         bool RELU, bool OUTF16, int SPLIT, bool ADDBIAS>
__global__ __launch_bounds__(256) void conv_mfma_kernel(const f16* __restrict__ in,
                                                        const f16* __restrict__ wt,
                                                        const float* __restrict__ bias,
                                                        f16* __restrict__ out16,
                                                        float* __restrict__ out32) {
  constexpr int KTOT = 81 * CIN;
  constexpr int NBLK = COUT / 128;
  constexpr int MTOT = 256 * HOUT * WOUT;
  constexpr int MBNB = (MTOT / 128) * NBLK;
  constexpr int NKT = (KTOT / 64) / SPLIT;
  __shared__ __align__(16) f16 lds[16384];
  int bidx = (int)blockIdx.x;
  int ks = 0;
  if (SPLIT > 1) { ks = bidx / MBNB; bidx -= ks * MBNB; }
  const int mb = bidx / NBLK;
  const int nb = bidx % NBLK;
  const int t = threadIdx.x;
  const int wave = t >> 6, lane = t & 63;
  const int hi = lane >> 4, lo = lane & 15;
  const bool isA = wave < 2;
  const int slot0 = wave << 9;

  int baseoff[8];
#pragma unroll
  for (int it = 0; it < 8; ++it) {
    int s = slot0 + it * 64 + lane;
    if (isA) {
      int row = s >> 3;
      int g = (s & 7) ^ (row & 7);
      int mg = mb * 128 + row;
      int b = mg / (HOUT * WOUT);
      int rr = mg - b * (HOUT * WOUT);
      int oh = rr / WOUT;
      int ow = rr - oh * WOUT;
      baseoff[it] = ((b * HIN + oh * STRIDE) * WIN + ow * STRIDE) * CIN + g * 8;
    } else {
      int sl = s - 1024;
      int row = sl >> 3;
      int g = (sl & 7) ^ (row & 7);
      baseoff[it] = (nb * 128 + row) * KTOT + g * 8;
    }
  }
  const f16* gsrc = isA ? in : wt;

  int aQ[4], bQ[4];
  const int wm = wave >> 1, wn = wave & 1;
#pragma unroll
  for (int f = 0; f < 4; ++f) {
    int arow = wm * 64 + f * 16 + lo;
    aQ[f] = (arow * 128) ^ ((arow & 7) << 4);
    int brow = wn * 64 + f * 16 + lo;
    bQ[f] = 16384 + ((brow * 128) ^ ((brow & 7) << 4));
  }

  f32x4 acc[4][4] = {};
  const char* ldsc = (const char*)lds;

  const int kt0 = ks * NKT;
  for (int kt = kt0; kt < kt0 + NKT; ++kt) {
    int tapoff;
    if (isA) tapoff = tapA_off<CIN, WIN>(kt);
    else     tapoff = kt << 6;
    __syncthreads();
#pragma unroll
    for (int it = 0; it < 8; ++it)
      gload_lds16(gsrc + baseoff[it] + tapoff,
                  (void*)((char*)lds + ((slot0 + it * 64) << 4)));
    __syncthreads();
#pragma unroll
    for (int sub = 0; sub < 2; ++sub) {
      const int gx = (sub * 4 + hi) << 4;
      f16x8 av[4], bv[4];
#pragma unroll
      for (int f = 0; f < 4; ++f) av[f] = *(const f16x8*)(ldsc + (aQ[f] ^ gx));
#pragma unroll
      for (int f = 0; f < 4; ++f) bv[f] = *(const f16x8*)(ldsc + (bQ[f] ^ gx));
#pragma unroll
      for (int mf = 0; mf < 4; ++mf)
#pragma unroll
        for (int nf = 0; nf < 4; ++nf)
          acc[mf][nf] = __builtin_amdgcn_mfma_f32_16x16x32_f16(av[mf], bv[nf],
                                                               acc[mf][nf], 0, 0, 0);
    }
  }

  float* o32 = out32 + (size_t)ks * MTOT * COUT;
#pragma unroll
  for (int mf = 0; mf < 4; ++mf) {
#pragma unroll
    for (int nf = 0; nf < 4; ++nf) {
      int m0 = mb * 128 + wm * 64 + mf * 16 + hi * 4;
      int n = nb * 128 + wn * 64 + nf * 16 + lo;
      float bval = ADDBIAS ? bias[n] : 0.f;
#pragma unroll
      for (int r = 0; r < 4; ++r) {
        float v = acc[mf][nf][r] + bval;
        if (RELU) v = fmaxf(v, 0.f);
        int o = (m0 + r) * COUT + n;
        if (OUTF16) out16[o] = (f16)v; else o32[o] = v;
      }
    }
  }
}

// ---------------- prim K-split reduction: p = bias + sum_s partial[s] ----------------
__global__ __launch_bounds__(256) void prim_reduce_kernel(const float* __restrict__ part,
                                                          const float* __restrict__ bias,
                                                          float* __restrict__ p) {
  int idx = blockIdx.x * 256 + threadIdx.x;  // 9216*256
  int n = idx & 255;
  float a = bias[n];
#pragma unroll
  for (int s = 0; s < 4; ++s) a += part[s * 2359296 + idx];
  p[idx] = a;
}

// ---------------- dense GEMM via f16 MFMA: A[256][K] x Bw[NP][K]^T (+bias, act) -----
template<int K, int NP, int NOUT, int ACT>
__global__ __launch_bounds__(256) void gemm_mfma_kernel(const f16* __restrict__ A,
                                                        const f16* __restrict__ Bw,
                                                        const float* __restrict__ bias,
                                                        f16* __restrict__ out16,
                                                        float* __restrict__ out32) {
  constexpr int NBLK = NP / 128;
  __shared__ __align__(16) f16 lds[16384];
  const int mb = (int)blockIdx.x / NBLK;
  const int nb = (int)blockIdx.x % NBLK;
  const int t = threadIdx.x;
  const int wave = t >> 6, lane = t & 63;
  const int hi = lane >> 4, lo = lane & 15;
  const bool isA = wave < 2;
  const int slot0 = wave << 9;

  int baseoff[8];
#pragma unroll
  for (int it = 0; it < 8; ++it) {
    int s = slot0 + it * 64 + lane;
    if (isA) {
      int row = s >> 3;
      int g = (s & 7) ^ (row & 7);
      baseoff[it] = (mb * 128 + row) * K + g * 8;
    } else {
      int sl = s - 1024;
      int row = sl >> 3;
      int g = (sl & 7) ^ (row & 7);
      baseoff[it] = (nb * 128 + row) * K + g * 8;
    }
  }
  const f16* gsrc = isA ? A : Bw;

  int aQ[4], bQ[4];
  const int wm = wave >> 1, wn = wave & 1;
#pragma unroll
  for (int f = 0; f < 4; ++f) {
    int arow = wm * 64 + f * 16 + lo;
    aQ[f] = (arow * 128) ^ ((arow & 7) << 4);
    int brow = wn * 64 + f * 16 + lo;
    bQ[f] = 16384 + ((brow * 128) ^ ((brow & 7) << 4));
  }

  f32x4 acc[4][4] = {};
  const char* ldsc = (const char*)lds;

  for (int kt = 0; kt < K / 64; ++kt) {
    int tapoff = kt << 6;
    __syncthreads();
#pragma unroll
    for (int it = 0; it < 8; ++it)
      gload_lds16(gsrc + baseoff[it] + tapoff,
                  (void*)((char*)lds + ((slot0 + it * 64) << 4)));
    __syncthreads();
#pragma unroll
    for (int sub = 0; sub < 2; ++sub) {
      const int gx = (sub * 4 + hi) << 4;
      f16x8 av[4], bv[4];
#pragma unroll
      for (int f = 0; f < 4; ++f) av[f] = *(const f16x8*)(ldsc + (aQ[f] ^ gx));
#pragma unroll
      for (int f = 0; f < 4; ++f) bv[f] = *(const f16x8*)(ldsc + (bQ[f] ^ gx));
#pragma unroll
      for (int mf = 0; mf < 4; ++mf)
#pragma unroll
        for (int nf = 0; nf < 4; ++nf)
          acc[mf][nf] = __builtin_amdgcn_mfma_f32_16x16x32_f16(av[mf], bv[nf],
                                                               acc[mf][nf], 0, 0, 0);
    }
  }

#pragma unroll
  for (int mf = 0; mf < 4; ++mf) {
#pragma unroll
    for (int nf = 0; nf < 4; ++nf) {
      int m0 = mb * 128 + wm * 64 + mf * 16 + hi * 4;
      int n = nb * 128 + wn * 64 + nf * 16 + lo;
      if (n < NOUT) {
        float bval = bias[n];
#pragma unroll
        for (int r = 0; r < 4; ++r) {
          float v = acc[mf][nf][r] + bval;
          if (ACT == 0) out16[(m0 + r) * NOUT + n] = (f16)fmaxf(v, 0.f);
          else          out32[(m0 + r) * NOUT + n] = 1.f / (1.f + expf(-v));
        }
      }
    }
  }
}

// ---------------- u_hat[b,i,j,k] = sum_v w[i,j,k,v]*u[b,i,v]  (f16 out) ----------
__global__ __launch_bounds__(256) void uhat_kernel(const f16* __restrict__ wf,
                                                   const float* __restrict__ u,
                                                   f16* __restrict__ uh) {
  int idx = blockIdx.x * 256 + threadIdx.x;  // 256*1152*160
  int bi = idx / 160;
  int jk = idx - bi * 160;
  int i = bi % 1152;
  const f16x8 wv = *(const f16x8*)(wf + (i * 160 + jk) * 8);
  const float4* uv = (const float4*)(u + bi * 8);
  float4 u0 = uv[0], u1 = uv[1];
  float acc = (float)wv[0] * u0.x + (float)wv[1] * u0.y + (float)wv[2] * u0.z +
              (float)wv[3] * u0.w + (float)wv[4] * u1.x + (float)wv[5] * u1.y +
              (float)wv[6] * u1.z + (float)wv[7] * u1.w;
  uh[idx] = (f16)acc;
}

// ---------------- routing pass A: c=softmax(b), s=sum_i c*u_hat, v=squash(s) ------
template<bool FIRST>
__global__ __launch_bounds__(512) void routeA_kernel(const f16* __restrict__ uh,
                                                     const float* __restrict__ blog,
                                                     float* __restrict__ vbuf,
                                                     float* __restrict__ vout) {
  __shared__ float csm[1152 * 10];
  __shared__ float sp[320];
  int b = blockIdx.x, t = threadIdx.x;
  for (int i = t; i < 1152; i += 512) {
    if (FIRST) {
#pragma unroll
      for (int j = 0; j < 10; ++j) csm[i * 10 + j] = 0.1f;
    } else {
      float l[10];
#pragma unroll
      for (int j = 0; j < 10; ++j) l[j] = blog[(b * 1152 + i) * 10 + j];
      float mx = l[0];
#pragma unroll
      for (int j = 1; j < 10; ++j) mx = fmaxf(mx, l[j]);
      float sum = 0.f;
#pragma unroll
      for (int j = 0; j < 10; ++j) { l[j] = expf(l[j] - mx); sum += l[j]; }
      float inv = 1.f / sum;
#pragma unroll
      for (int j = 0; j < 10; ++j) csm[i * 10 + j] = l[j] * inv;
    }
  }
  __syncthreads();
  if (t < 320) {
    int half = (t >= 160) ? 1 : 0;
    int jk = t - half * 160;
    int j = jk >> 4;
    const f16* up = uh + b * 184320 + jk;
    int i0 = half * 576;
    float s = 0.f;
    for (int i = i0; i < i0 + 576; i += 8) {
#pragma unroll
      for (int u = 0; u < 8; ++u)
        s += csm[(i + u) * 10 + j] * (float)up[(i + u) * 160];
    }
    sp[t] = s;
  }
  __syncthreads();
  if (t < 160) {
    float s = sp[t] + sp[t + 160];
    float ss = s * s;
    ss += __shfl_xor(ss, 1, 16);
    ss += __shfl_xor(ss, 2, 16);
    ss += __shfl_xor(ss, 4, 16);
    ss += __shfl_xor(ss, 8, 16);
    float n = sqrtf(ss);
    float f = ss / ((1.f + ss) * (n + 1e-7f));
    float v = f * s;
    vbuf[b * 160 + t] = v;
    vout[b * 160 + t] = v;
  }
}

// ---------------- routing pass B: b_logit (+)= sum_k u_hat*v ----------------
template<bool ACCUM>
__global__ __launch_bounds__(256) void routeB_kernel(const f16* __restrict__ uh,
                                                     const float* __restrict__ vbuf,
                                                     float* __restrict__ blog) {
  int idx = blockIdx.x * 256 + threadIdx.x;  // 256*1152
  int b = idx / 1152;
  float agr[10] = {};
  const f16x8* row = (const f16x8*)(uh + idx * 160);
  const float* vb = vbuf + b * 160;
#pragma unroll
  for (int c8 = 0; c8 < 20; ++c8) {
    f16x8 ch = row[c8];
#pragma unroll
    for (int e = 0; e < 8; ++e) {
      int jk = c8 * 8 + e;
      agr[jk >> 4] += (float)ch[e] * vb[jk];
    }
  }
#pragma unroll
  for (int j = 0; j < 10; ++j) {
    int o = idx * 10 + j;
    blog[o] = (ACCUM ? blog[o] : 0.f) + agr[j];
  }
}

// ---------------- mask by label + dense1 (160->1024, relu, f16 out) ----------------
__global__ __launch_bounds__(256) void maskd1_kernel(const float* __restrict__ vbuf,
                                                     const int* __restrict__ y,
                                                     const float* __restrict__ w1,
                                                     const float* __restrict__ b1,
                                                     f16* __restrict__ r1) {
  int idx = blockIdx.x * 256 + threadIdx.x;  // 256*1024
  int o = idx & 1023;
  int b = idx >> 10;
  int yb = y[b];
  const float* vv = vbuf + b * 160 + yb * 16;
  float acc = b1[o];
#pragma unroll
  for (int k = 0; k < 16; ++k) acc += vv[k] * w1[(yb * 16 + k) * 1024 + o];
  r1[idx] = (f16)fmaxf(acc, 0.f);
}

// ---------------- launch ----------------
extern "C" void kernel_launch(void* const* d_in, const int* in_sizes, int n_in,
                              void* d_out, int out_size, void* d_ws, size_t ws_size,
                              hipStream_t stream) {
  const float* x       = (const float*)d_in[0];
  const int*   y       = (const int*)d_in[1];
  const float* conv1_k = (const float*)d_in[2];
  const float* conv1_b = (const float*)d_in[3];
  const float* conv2_k = (const float*)d_in[4];
  const float* conv2_b = (const float*)d_in[5];
  const float* conv3_k = (const float*)d_in[6];
  const float* conv3_b = (const float*)d_in[7];
  const float* prim_k  = (const float*)d_in[8];
  const float* prim_b  = (const float*)d_in[9];
  const float* w_route = (const float*)d_in[10];
  const float* d1_w = (const float*)d_in[11];
  const float* d1_b = (const float*)d_in[12];
  const float* d2_w = (const float*)d_in[13];
  const float* d2_b = (const float*)d_in[14];
  const float* d3_w = (const float*)d_in[15];
  const float* d3_b = (const float*)d_in[16];

  // workspace layout (bytes), total 191,021,056 (same as R1-R5 -> proven fits):
  //   ws+0: h1 (dead after conv2) -> conv3 tail partials (37.75MB) -> prim part -> uhat
  char* ws = (char*)d_ws;
  f16*   h1    = (f16*)(ws + 0);
  f16*   tpart = (f16*)(ws + 0);                     // 37,748,736 B (h1 dead)
  f16*   h2    = (f16*)(ws + 42467328);
  f16*   h3    = (f16*)(ws + 93847552);
  float* part  = (float*)(ws + 0);                   // 4 x 9,437,184 B (tpart dead)
  f16*   uhat  = (f16*)(ws + 0);                     // 94,371,840 B (alias)
  float* p     = (float*)(ws + 146276352);           //  9,437,184 B
  float* blog  = (float*)(ws + 155713536);           // 11,796,480 B
  f16*   wd2   = (f16*)(ws + 155713536);             //  4,194,304 B (alias, post-routing)
  f16*   wd3   = (f16*)(ws + 159907840);             //  6,815,744 B (alias, post-routing)
  float* vbuf  = (float*)(ws + 167510016);           //    163,840 B
  f16*   r1h   = (f16*)(ws + 167673856);             //    524,288 B
  f16*   r2h   = (f16*)(ws + 168198144);             //  1,048,576 B
  f16*   wt2   = (f16*)(ws + 170819584);             //  1,327,104 B
  f16*   wt3   = (f16*)(ws + 172146688);             //  5,308,416 B
  f16*   wtp   = (f16*)(ws + 177455104);             // 10,616,832 B
  f16*   wf16  = (f16*)(ws + 188071936);             //  2,949,120 B -> 191,021,056

  float* vout  = (float*)d_out;            // [256,1,10,16] = 40960 f32
  float* recon = (float*)d_out + 40960;    // [256,1600]

  // weight prep
  wtrans_kernel<64, 128><<<dim3(81, 2), 256, 0, stream>>>(conv2_k, wt2);
  wtrans_kernel<128, 256><<<dim3(162, 4), 256, 0, stream>>>(conv3_k, wt3);
  wtrans_kernel<256, 256><<<dim3(324, 4), 256, 0, stream>>>(prim_k, wtp);
  cvtf16_kernel<<<5760, 256, 0, stream>>>(w_route, wf16, 1474560);

  // conv stack
  conv1_kernel<<<10368, 256, 0, stream>>>(x, conv1_k, conv1_b, h1);
  // conv2: m97 128x128 (multi-resident, best measured for COUT=128)
  conv_mfma_kernel<36, 36, 64, 28, 28, 128, 1, true, true, 1, true>
      <<<1568, 256, 0, stream>>>(h1, wt2, conv2_b, h2, nullptr);
  // conv3: 8-phase 256^2 + tail K-split smoothing (256 full + 288 half blocks)
  conv8p_kernel<28, 28, 128, 20, 20, 256, 1, true, true, 256, 144>
      <<<544, 512, 0, stream>>>(h2, wt3, conv3_b, h3, nullptr, tpart);
  tailred_kernel<<<4608, 256, 0, stream>>>(tpart, conv3_b, h3);
  // prim caps: K-split x4 (m97 structure), partials + reduce
  conv_mfma_kernel<20, 20, 256, 6, 6, 256, 2, false, false, 4, false>
      <<<576, 256, 0, stream>>>(h3, wtp, prim_b, nullptr, part);
  prim_reduce_kernel<<<9216, 256, 0, stream>>>(part, prim_b, p);

  // capsule predictions + dynamic routing (R=3; last agreement is dead -> skipped)
  uhat_kernel<<<184320, 256, 0, stream>>>(wf16, p, uhat);
  routeA_kernel<true><<<256, 512, 0, stream>>>(uhat, blog, vbuf, vout);
  routeB_kernel<false><<<1152, 256, 0, stream>>>(uhat, vbuf, blog);
  routeA_kernel<false><<<256, 512, 0, stream>>>(uhat, blog, vbuf, vout);
  routeB_kernel<true><<<1152, 256, 0, stream>>>(uhat, vbuf, blog);
  routeA_kernel<false><<<256, 512, 0, stream>>>(uhat, blog, vbuf, vout);

  // masked reconstruction (dense weights -> f16 [N][K] into dead blog region)
  wtransg_kernel<<<dim3(16, 32), 256, 0, stream>>>(d2_w, wd2, 1024, 2048, 2048);
  wtransg_kernel<<<dim3(32, 26), 256, 0, stream>>>(d3_w, wd3, 2048, 1600, 1664);
  maskd1_kernel<<<1024, 256, 0, stream>>>(vbuf, y, d1_w, d1_b, r1h);
  gemm_mfma_kernel<1024, 2048, 2048, 0><<<32, 256, 0, stream>>>(r1h, wd2, d2_b, r2h, nullptr);
  gemm_mfma_kernel<2048, 1664, 1600, 1><<<26, 256, 0, stream>>>(r2h, wd3, d3_b, nullptr, recon);
}

// Round 7
// 1257.433 us; speedup vs baseline: 1.1434x; 1.1110x over previous
//
#include <hip/hip_runtime.h>
#include <hip/hip_bf16.h>

typedef _Float16 f16;
typedef __attribute__((ext_vector_type(8))) _Float16 f16x8;
typedef __attribute__((ext_vector_type(4))) float f32x4;

// ---------------- global_load_lds helper (16B, wave-uniform LDS base + lane*16) ----
__device__ __forceinline__ void gload_lds16(const void* g, void* l) {
  __builtin_amdgcn_global_load_lds((const __attribute__((address_space(1))) void*)g,
                                   (__attribute__((address_space(3))) void*)l, 16, 0, 0);
}

// ---------------- weight transpose+cast: [81*CIN][COUT] f32 -> [COUT][81*CIN] f16 --
template<int CIN, int COUT>
__global__ __launch_bounds__(256) void wtrans_kernel(const float* __restrict__ src,
                                                     f16* __restrict__ dst) {
  constexpr int KT = 81 * CIN;
  __shared__ float tile[64][65];
  int k0 = blockIdx.x * 64;
  int n0 = blockIdx.y * 64;
  int t = threadIdx.x;
#pragma unroll
  for (int i = 0; i < 16; ++i) {
    int id = t + i * 256;
    int r = id >> 6, c = id & 63;
    tile[r][c] = src[(k0 + r) * COUT + n0 + c];
  }
  __syncthreads();
#pragma unroll
  for (int i = 0; i < 16; ++i) {
    int id = t + i * 256;
    int r = id >> 6, c = id & 63;  // r = n_local, c = k_local
    dst[(n0 + r) * KT + k0 + c] = (f16)tile[c][r];
  }
}

// ---------------- generic transpose+cast+pad: [K][N] f32 -> [NP][K] f16, zero rows n>=N
__global__ __launch_bounds__(256) void wtransg_kernel(const float* __restrict__ src,
                                                      f16* __restrict__ dst,
                                                      int K, int N, int NP) {
  __shared__ float tile[64][65];
  int k0 = blockIdx.x * 64;
  int n0 = blockIdx.y * 64;
  int t = threadIdx.x;
#pragma unroll
  for (int i = 0; i < 16; ++i) {
    int id = t + i * 256;
    int r = id >> 6, c = id & 63;  // r = k_local, c = n_local
    tile[r][c] = (n0 + c < N) ? src[(k0 + r) * N + n0 + c] : 0.f;
  }
  __syncthreads();
#pragma unroll
  for (int i = 0; i < 16; ++i) {
    int id = t + i * 256;
    int r = id >> 6, c = id & 63;  // r = n_local, c = k_local
    dst[(size_t)(n0 + r) * K + k0 + c] = (f16)tile[c][r];
  }
}

// ---------------- plain f32 -> f16 cast copy ----------------
__global__ __launch_bounds__(256) void cvtf16_kernel(const float* __restrict__ src,
                                                     f16* __restrict__ dst, int n) {
  int idx = blockIdx.x * 256 + threadIdx.x;
  if (idx < n) dst[idx] = (f16)src[idx];
}

// ---------------- conv1: 5x5, Cin=1, Cout=64, relu, f16 out (8 couts/thread) -------
__global__ __launch_bounds__(256) void conv1_kernel(const float* __restrict__ x,
                                                    const float* __restrict__ kw,
                                                    const float* __restrict__ bias,
                                                    f16* __restrict__ out) {
  int idx = blockIdx.x * 256 + threadIdx.x;  // 256*36*36*8 threads
  int g = idx & 7;
  int co0 = g * 8;
  int r = idx >> 3;
  int ow = r % 36; int r2 = r / 36; int oh = r2 % 36; int b = r2 / 36;
  float acc[8];
#pragma unroll
  for (int j = 0; j < 8; ++j) acc[j] = bias[co0 + j];
  const float* xp = x + (b * 40 + oh) * 40 + ow;
#pragma unroll
  for (int dy = 0; dy < 5; ++dy)
#pragma unroll
    for (int dx = 0; dx < 5; ++dx) {
      float xv = xp[dy * 40 + dx];
      const float* kp = kw + (dy * 5 + dx) * 64 + co0;
#pragma unroll
      for (int j = 0; j < 8; ++j) acc[j] += xv * kp[j];
    }
  f16x8 o;
#pragma unroll
  for (int j = 0; j < 8; ++j) o[j] = (f16)fmaxf(acc[j], 0.f);
  *(f16x8*)(out + r * 64 + co0) = o;
}

// ---------------- im2col tap offset helper (BK=64 chunks) ----------------
template<int CIN, int WIN>
__device__ __forceinline__ int tapA_off(int kt) {
  int tap, ci0;
  if (CIN == 64)       { tap = kt;      ci0 = 0; }
  else if (CIN == 128) { tap = kt >> 1; ci0 = (kt & 1) << 6; }
  else                 { tap = kt >> 2; ci0 = (kt & 3) << 6; }
  int dy = tap / 9, dx = tap - dy * 9;
  return (dy * WIN + dx) * CIN + ci0;
}

// ============ 8-phase 256x256 implicit-GEMM conv (HK-template port, R3 config) ======
// BM=BN=256, BK=64, 8 waves (2Mx4N), per-wave C = 128x64 (acc[8][4] f32x4).
// LDS 128KB: A bufs [0,64K), B bufs [64K,128K). XOR-swizzle byte^=((row&7)<<4).
template<int HIN, int WIN, int CIN, int HOUT, int WOUT, int COUT, int STRIDE,
         bool RELU, bool OUTF16>
__global__ __launch_bounds__(512, 2) void conv8p_kernel(const f16* __restrict__ in,
                                                        const f16* __restrict__ wt,
                                                        const float* __restrict__ bias,
                                                        f16* __restrict__ out16,
                                                        float* __restrict__ out32) {
  static_assert(COUT == 256, "BN=256 template requires COUT==256");
  constexpr int KTOT = 81 * CIN;
  constexpr int NT = KTOT / 64;
  __shared__ __align__(16) f16 lds[65536];  // 128 KiB
  const int mb = (int)blockIdx.x;
  const int t = threadIdx.x;
  const int wave = t >> 6, lane = t & 63;
  const int hi = lane >> 4, lo = lane & 15;
  const int wm = wave >> 2, wn = wave & 3;

  int Aoff[4], Boff[4];
  {
    int g = (lane & 7) ^ ((lane >> 3) & 7);  // inverse swizzle granule
#pragma unroll
    for (int rbi = 0; rbi < 4; ++rbi) {
      int r = rbi * 64 + 8 * wave + (lane >> 3);
      int m = mb * 256 + r;
      int b = m / (HOUT * WOUT);
      int rr = m - b * (HOUT * WOUT);
      int oh = rr / WOUT, ow = rr - oh * WOUT;
      Aoff[rbi] = ((b * HIN + oh * STRIDE) * WIN + ow * STRIDE) * CIN + g * 8;
      Boff[rbi] = r * KTOT + g * 8;
    }
  }
  const int gb0 = (hi ^ (lo & 7)) << 4;
  const int gb1 = ((4 + hi) ^ (lo & 7)) << 4;

  const char* ldsc = (const char*)lds;
  char* ldsw = (char*)lds;

#define GA(rbi, tpo, bq) gload_lds16(in + Aoff[rbi] + (tpo),                        \
    (void*)(ldsw + (bq) * 32768 + ((rbi) * 64 + 8 * wave) * 128))
#define GB(rbi, tile) gload_lds16(wt + Boff[rbi] + ((tile) << 6),                   \
    (void*)(ldsw + 65536 + ((tile) & 1) * 32768 + ((rbi) * 64 + 8 * wave) * 128))

  {
    int tp0 = tapA_off<CIN, WIN>(0);
    GA(0, tp0, 0); GA(2, tp0, 0); GA(1, tp0, 0); GA(3, tp0, 0);
    GB(0, 0); GB(1, 0); GB(2, 0); GB(3, 0);
    GB(0, 1); GB(1, 1); GB(2, 1); GB(3, 1);
    asm volatile("s_waitcnt vmcnt(4)" ::: "memory");
    __builtin_amdgcn_s_barrier();
  }

  f32x4 acc[8][4] = {};

#define DO_PHASE(Q, STAGE)                                                          \
  {                                                                                 \
    f16x8 af[2][2];                                                                 \
    _Pragma("unroll")                                                               \
    for (int mf = 0; mf < 2; ++mf) {                                                \
      af[mf][0] = *(const f16x8*)(Ab + ((Q) * 2 + mf) * 2048 + gb0);                \
      af[mf][1] = *(const f16x8*)(Ab + ((Q) * 2 + mf) * 2048 + gb1);                \
    }                                                                               \
    STAGE;                                                                          \
    __builtin_amdgcn_s_barrier();                                                   \
    asm volatile("s_waitcnt lgkmcnt(0)" ::: "memory");                              \
    __builtin_amdgcn_sched_barrier(0);                                              \
    __builtin_amdgcn_s_setprio(1);                                                  \
    _Pragma("unroll")                                                               \
    for (int sb = 0; sb < 2; ++sb)                                                  \
      _Pragma("unroll")                                                             \
      for (int mf = 0; mf < 2; ++mf)                                                \
        _Pragma("unroll")                                                           \
        for (int nf = 0; nf < 4; ++nf)                                              \
          acc[(Q) * 2 + mf][nf] = __builtin_amdgcn_mfma_f32_16x16x32_f16(           \
              af[mf][sb], bfr[nf][sb], acc[(Q) * 2 + mf][nf], 0, 0, 0);             \
    __builtin_amdgcn_s_setprio(0);                                                  \
    __builtin_amdgcn_s_barrier();                                                   \
  }

  for (int T = 0; T < NT; ++T) {
    const int q = T & 1;
    const char* Ab = ldsc + q * 32768 + wm * 16384 + lo * 128;
    const char* Bb = ldsc + 65536 + q * 32768 + wn * 8192 + lo * 128;
    const int tpn = tapA_off<CIN, WIN>(T + 1);
    f16x8 bfr[4][2];
#pragma unroll
    for (int nf = 0; nf < 4; ++nf) {
      bfr[nf][0] = *(const f16x8*)(Bb + nf * 2048 + gb0);
      bfr[nf][1] = *(const f16x8*)(Bb + nf * 2048 + gb1);
    }
    DO_PHASE(0, if (T + 1 < NT) { GA(0, tpn, (T + 1) & 1); GA(2, tpn, (T + 1) & 1); })
    DO_PHASE(1, if (T + 1 < NT) { GA(1, tpn, (T + 1) & 1); GA(3, tpn, (T + 1) & 1); })
    DO_PHASE(2, if (T + 2 < NT) { GB(0, T + 2); GB(1, T + 2); })
    DO_PHASE(3,
      if (T + 2 < NT) {
        GB(2, T + 2); GB(3, T + 2);
        asm volatile("s_waitcnt vmcnt(4)" ::: "memory");
      } else {
        asm volatile("s_waitcnt vmcnt(0)" ::: "memory");
      })
  }
#undef DO_PHASE
#undef GA
#undef GB

#pragma unroll
  for (int mfr = 0; mfr < 8; ++mfr) {
#pragma unroll
    for (int nf = 0; nf < 4; ++nf) {
      int m0 = mb * 256 + wm * 128 + mfr * 16 + hi * 4;
      int n = wn * 64 + nf * 16 + lo;
      float bval = bias[n];
#pragma unroll
      for (int r = 0; r < 4; ++r) {
        float v = acc[mfr][nf][r] + bval;
        if (RELU) v = fmaxf(v, 0.f);
        int o = (m0 + r) * COUT + n;
        if (OUTF16) out16[o] = (f16)v; else out32[o] = v;
      }
    }
  }
}

// ---------------- implicit-GEMM conv via f16 MFMA (m97 structure, 128x128) --------
template<int HIN, int WIN, int CIN, int HOUT, int WOUT, int COUT, int STRIDE,
         bool RELU, bool OUTF16, int SPLIT, bool ADDBIAS>
__global__ __launch_bounds__(256) void conv_mfma_kernel(const f16* __restrict__ in,
                                                        const f16* __restrict__ wt,
                                                        const float* __restrict__ bias,
                                                        f16* __restrict__ out16,
                                                        float* __restrict__ out32) {
  constexpr int KTOT = 81 * CIN;
  constexpr int NBLK = COUT / 128;
  constexpr int MTOT = 256 * HOUT * WOUT;
  constexpr int MBNB = (MTOT / 128) * NBLK;
  constexpr int NKT = (KTOT / 64) / SPLIT;
  __shared__ __align__(16) f16 lds[16384];
  int bidx = (int)blockIdx.x;
  int ks = 0;
  if (SPLIT > 1) { ks = bidx / MBNB; bidx -= ks * MBNB; }
  const int mb = bidx / NBLK;
  const int nb = bidx % NBLK;
  const int t = threadIdx.x;
  const int wave = t >> 6, lane = t & 63;
  const int hi = lane >> 4, lo = lane & 15;
  const bool isA = wave < 2;
  const int slot0 = wave << 9;

  int baseoff[8];
#pragma unroll
  for (int it = 0; it < 8; ++it) {
    int s = slot0 + it * 64 + lane;
    if (isA) {
      int row = s >> 3;
      int g = (s & 7) ^ (row & 7);
      int mg = mb * 128 + row;
      int b = mg / (HOUT * WOUT);
      int rr = mg - b * (HOUT * WOUT);
      int oh = rr / WOUT;
      int ow = rr - oh * WOUT;
      baseoff[it] = ((b * HIN + oh * STRIDE) * WIN + ow * STRIDE) * CIN + g * 8;
    } else {
      int sl = s - 1024;
      int row = sl >> 3;
      int g = (sl & 7) ^ (row & 7);
      baseoff[it] = (nb * 128 + row) * KTOT + g * 8;
    }
  }
  const f16* gsrc = isA ? in : wt;

  int aQ[4], bQ[4];
  const int wm = wave >> 1, wn = wave & 1;
#pragma unroll
  for (int f = 0; f < 4; ++f) {
    int arow = wm * 64 + f * 16 + lo;
    aQ[f] = (arow * 128) ^ ((arow & 7) << 4);
    int brow = wn * 64 + f * 16 + lo;
    bQ[f] = 16384 + ((brow * 128) ^ ((brow & 7) << 4));
  }

  f32x4 acc[4][4] = {};
  const char* ldsc = (const char*)lds;

  const int kt0 = ks * NKT;
  for (int kt = kt0; kt < kt0 + NKT; ++kt) {
    int tapoff;
    if (isA) tapoff = tapA_off<CIN, WIN>(kt);
    else     tapoff = kt << 6;
    __syncthreads();
#pragma unroll
    for (int it = 0; it < 8; ++it)
      gload_lds16(gsrc + baseoff[it] + tapoff,
                  (void*)((char*)lds + ((slot0 + it * 64) << 4)));
    __syncthreads();
#pragma unroll
    for (int sub = 0; sub < 2; ++sub) {
      const int gx = (sub * 4 + hi) << 4;
      f16x8 av[4], bv[4];
#pragma unroll
      for (int f = 0; f < 4; ++f) av[f] = *(const f16x8*)(ldsc + (aQ[f] ^ gx));
#pragma unroll
      for (int f = 0; f < 4; ++f) bv[f] = *(const f16x8*)(ldsc + (bQ[f] ^ gx));
#pragma unroll
      for (int mf = 0; mf < 4; ++mf)
#pragma unroll
        for (int nf = 0; nf < 4; ++nf)
          acc[mf][nf] = __builtin_amdgcn_mfma_f32_16x16x32_f16(av[mf], bv[nf],
                                                               acc[mf][nf], 0, 0, 0);
    }
  }

  float* o32 = out32 + (size_t)ks * MTOT * COUT;
#pragma unroll
  for (int mf = 0; mf < 4; ++mf) {
#pragma unroll
    for (int nf = 0; nf < 4; ++nf) {
      int m0 = mb * 128 + wm * 64 + mf * 16 + hi * 4;
      int n = nb * 128 + wn * 64 + nf * 16 + lo;
      float bval = ADDBIAS ? bias[n] : 0.f;
#pragma unroll
      for (int r = 0; r < 4; ++r) {
        float v = acc[mf][nf][r] + bval;
        if (RELU) v = fmaxf(v, 0.f);
        int o = (m0 + r) * COUT + n;
        if (OUTF16) out16[o] = (f16)v; else o32[o] = v;
      }
    }
  }
}

// ---------------- prim K-split reduction: p = bias + sum_s partial[s] ----------------
__global__ __launch_bounds__(256) void prim_reduce_kernel(const float* __restrict__ part,
                                                          const float* __restrict__ bias,
                                                          float* __restrict__ p) {
  int idx = blockIdx.x * 256 + threadIdx.x;  // 9216*256
  int n = idx & 255;
  float a = bias[n];
#pragma unroll
  for (int s = 0; s < 4; ++s) a += part[s * 2359296 + idx];
  p[idx] = a;
}

// ---------------- dense GEMM via f16 MFMA: A[256][K] x Bw[NP][K]^T (+bias, act) -----
template<int K, int NP, int NOUT, int ACT>
__global__ __launch_bounds__(256) void gemm_mfma_kernel(const f16* __restrict__ A,
                                                        const f16* __restrict__ Bw,
                                                        const float* __restrict__ bias,
                                                        f16* __restrict__ out16,
                                                        float* __restrict__ out32) {
  constexpr int NBLK = NP / 128;
  __shared__ __align__(16) f16 lds[16384];
  const int mb = (int)blockIdx.x / NBLK;
  const int nb = (int)blockIdx.x % NBLK;
  const int t = threadIdx.x;
  const int wave = t >> 6, lane = t & 63;
  const int hi = lane >> 4, lo = lane & 15;
  const bool isA = wave < 2;
  const int slot0 = wave << 9;

  int baseoff[8];
#pragma unroll
  for (int it = 0; it < 8; ++it) {
    int s = slot0 + it * 64 + lane;
    if (isA) {
      int row = s >> 3;
      int g = (s & 7) ^ (row & 7);
      baseoff[it] = (mb * 128 + row) * K + g * 8;
    } else {
      int sl = s - 1024;
      int row = sl >> 3;
      int g = (sl & 7) ^ (row & 7);
      baseoff[it] = (nb * 128 + row) * K + g * 8;
    }
  }
  const f16* gsrc = isA ? A : Bw;

  int aQ[4], bQ[4];
  const int wm = wave >> 1, wn = wave & 1;
#pragma unroll
  for (int f = 0; f < 4; ++f) {
    int arow = wm * 64 + f * 16 + lo;
    aQ[f] = (arow * 128) ^ ((arow & 7) << 4);
    int brow = wn * 64 + f * 16 + lo;
    bQ[f] = 16384 + ((brow * 128) ^ ((brow & 7) << 4));
  }

  f32x4 acc[4][4] = {};
  const char* ldsc = (const char*)lds;

  for (int kt = 0; kt < K / 64; ++kt) {
    int tapoff = kt << 6;
    __syncthreads();
#pragma unroll
    for (int it = 0; it < 8; ++it)
      gload_lds16(gsrc + baseoff[it] + tapoff,
                  (void*)((char*)lds + ((slot0 + it * 64) << 4)));
    __syncthreads();
#pragma unroll
    for (int sub = 0; sub < 2; ++sub) {
      const int gx = (sub * 4 + hi) << 4;
      f16x8 av[4], bv[4];
#pragma unroll
      for (int f = 0; f < 4; ++f) av[f] = *(const f16x8*)(ldsc + (aQ[f] ^ gx));
#pragma unroll
      for (int f = 0; f < 4; ++f) bv[f] = *(const f16x8*)(ldsc + (bQ[f] ^ gx));
#pragma unroll
      for (int mf = 0; mf < 4; ++mf)
#pragma unroll
        for (int nf = 0; nf < 4; ++nf)
          acc[mf][nf] = __builtin_amdgcn_mfma_f32_16x16x32_f16(av[mf], bv[nf],
                                                               acc[mf][nf], 0, 0, 0);
    }
  }

#pragma unroll
  for (int mf = 0; mf < 4; ++mf) {
#pragma unroll
    for (int nf = 0; nf < 4; ++nf) {
      int m0 = mb * 128 + wm * 64 + mf * 16 + hi * 4;
      int n = nb * 128 + wn * 64 + nf * 16 + lo;
      if (n < NOUT) {
        float bval = bias[n];
#pragma unroll
        for (int r = 0; r < 4; ++r) {
          float v = acc[mf][nf][r] + bval;
          if (ACT == 0) out16[(m0 + r) * NOUT + n] = (f16)fmaxf(v, 0.f);
          else          out32[(m0 + r) * NOUT + n] = 1.f / (1.f + expf(-v));
        }
      }
    }
  }
}

// ======================= fused routing =======================
// uhatps: block (b, ic of 9), 320 threads. Computes uhat[b, ic*128..+128, :] and
// per-half-chunk partial sums over i -> parts[b][18][160].
__global__ __launch_bounds__(320) void uhatps_kernel(const f16* __restrict__ wf,
                                                     const float* __restrict__ u,
                                                     f16* __restrict__ uh,
                                                     float* __restrict__ parts) {
  __shared__ float pl[128][8];
  int blk = (int)blockIdx.x;
  int b = blk / 9, ic = blk - b * 9;
  int t = threadIdx.x;
  const float* pb = u + (b * 1152 + ic * 128) * 8;
  for (int e = t; e < 1024; e += 320) pl[e >> 3][e & 7] = pb[e];
  __syncthreads();
  int half = (t >= 160) ? 1 : 0;
  int jk = t - half * 160;
  int ibase = ic * 128 + half * 64;
  float sum = 0.f;
  for (int il = 0; il < 64; ++il) {
    int i = ibase + il;
    f16x8 wv = *(const f16x8*)(wf + (i * 160 + jk) * 8);
    const float* pr = pl[half * 64 + il];
    float acc = (float)wv[0] * pr[0] + (float)wv[1] * pr[1] + (float)wv[2] * pr[2] +
                (float)wv[3] * pr[3] + (float)wv[4] * pr[4] + (float)wv[5] * pr[5] +
                (float)wv[6] * pr[6] + (float)wv[7] * pr[7];
    uh[(b * 1152 + i) * 160 + jk] = (f16)acc;
    sum += acc;
  }
  parts[(b * 18 + ic * 2 + half) * 160 + jk] = sum;
}

// sred: s[b,jk] = cscale * sum_c parts[b][c][jk]; v = squash(s) -> vbuf (+vout last)
__global__ __launch_bounds__(160) void sred_kernel(const float* __restrict__ parts,
                                                   float cscale, int nch,
                                                   float* __restrict__ vbuf,
                                                   float* __restrict__ vout) {
  int b = blockIdx.x, t = threadIdx.x;  // t < 160
  float s = 0.f;
  for (int c = 0; c < nch; ++c) s += parts[(b * nch + c) * 160 + t];
  s *= cscale;
  float ss = s * s;
  ss += __shfl_xor(ss, 1, 16);
  ss += __shfl_xor(ss, 2, 16);
  ss += __shfl_xor(ss, 4, 16);
  ss += __shfl_xor(ss, 8, 16);
  float n = sqrtf(ss);
  float f = ss / ((1.f + ss) * (n + 1e-7f));
  float v = f * s;
  vbuf[b * 160 + t] = v;
  if (vout) vout[b * 160 + t] = v;
}

// ba: one uhat read does: agr = <uhat, v_prev>; blog' = blog + agr; c = softmax_j;
// partial s = sum_i c * uhat  ->  parts[b][9][160].  Deterministic (no atomics).
// LDS uhat tile padded to stride 172 f16 (agr-phase b128 reads <=4-way conflicts).
template<bool FIRST, bool WRITEB>
__global__ __launch_bounds__(256) void ba_kernel(const f16* __restrict__ uh,
                                                 const float* __restrict__ vbuf,
                                                 float* __restrict__ blog,
                                                 float* __restrict__ parts) {
  __shared__ f16 ul[128 * 172];   // 44,032 B
  __shared__ float vl[160];
  __shared__ float csm[128 * 10];
  int blk = (int)blockIdx.x;
  int b = blk / 9, ic = blk - b * 9;
  int t = threadIdx.x;
  const f16* ub = uh + (size_t)(b * 1152 + ic * 128) * 160;
  for (int e = t; e < 2560; e += 256) {  // 128 rows x 20 vec8
    int row = e / 20, col = e - row * 20;
    *(f16x8*)(ul + row * 172 + col * 8) = *(const f16x8*)(ub + row * 160 + col * 8);
  }
  if (t < 160) vl[t] = vbuf[b * 160 + t];
  __syncthreads();

  int il = t >> 1, half = t & 1, j0 = half * 5;
  const f16* ur = ul + il * 172 + j0 * 16;
  float agr[5];
#pragma unroll
  for (int j = 0; j < 5; ++j) {
    f16x8 a0 = *(const f16x8*)(ur + j * 16);
    f16x8 a1 = *(const f16x8*)(ur + j * 16 + 8);
    const float* vv = vl + (j0 + j) * 16;
    float s = (float)a0[0] * vv[0] + (float)a0[1] * vv[1] + (float)a0[2] * vv[2] +
              (float)a0[3] * vv[3] + (float)a0[4] * vv[4] + (float)a0[5] * vv[5] +
              (float)a0[6] * vv[6] + (float)a0[7] * vv[7] +
              (float)a1[0] * vv[8] + (float)a1[1] * vv[9] + (float)a1[2] * vv[10] +
              (float)a1[3] * vv[11] + (float)a1[4] * vv[12] + (float)a1[5] * vv[13] +
              (float)a1[6] * vv[14] + (float)a1[7] * vv[15];
    agr[j] = s;
  }
  int bbase = (b * 1152 + ic * 128 + il) * 10 + j0;
  float bl[5];
#pragma unroll
  for (int j = 0; j < 5; ++j) bl[j] = (FIRST ? 0.f : blog[bbase + j]) + agr[j];
  if (WRITEB) {
#pragma unroll
    for (int j = 0; j < 5; ++j) blog[bbase + j] = bl[j];
  }
  float mx = bl[0];
#pragma unroll
  for (int j = 1; j < 5; ++j) mx = fmaxf(mx, bl[j]);
  mx = fmaxf(mx, __shfl_xor(mx, 1));
  float e5[5], se = 0.f;
#pragma unroll
  for (int j = 0; j < 5; ++j) { e5[j] = expf(bl[j] - mx); se += e5[j]; }
  se += __shfl_xor(se, 1);
  float inv = 1.f / se;
#pragma unroll
  for (int j = 0; j < 5; ++j) csm[il * 10 + j0 + j] = e5[j] * inv;
  __syncthreads();

  if (t < 160) {
    int j = t >> 4;
    float s = 0.f;
    for (int il2 = 0; il2 < 128; ++il2)
      s += csm[il2 * 10 + j] * (float)ul[il2 * 172 + t];
    parts[(b * 9 + ic) * 160 + t] = s;
  }
}

// ---------------- mask by label + dense1 (160->1024, relu, f16 out) ----------------
__global__ __launch_bounds__(256) void maskd1_kernel(const float* __restrict__ vbuf,
                                                     const int* __restrict__ y,
                                                     const float* __restrict__ w1,
                                                     const float* __restrict__ b1,
                                                     f16* __restrict__ r1) {
  int idx = blockIdx.x * 256 + threadIdx.x;  // 256*1024
  int o = idx & 1023;
  int b = idx >> 10;
  int yb = y[b];
  const float* vv = vbuf + b * 160 + yb * 16;
  float acc = b1[o];
#pragma unroll
  for (int k = 0; k < 16; ++k) acc += vv[k] * w1[(yb * 16 + k) * 1024 + o];
  r1[idx] = (f16)fmaxf(acc, 0.f);
}

// ---------------- launch ----------------
extern "C" void kernel_launch(void* const* d_in, const int* in_sizes, int n_in,
                              void* d_out, int out_size, void* d_ws, size_t ws_size,
                              hipStream_t stream) {
  const float* x       = (const float*)d_in[0];
  const int*   y       = (const int*)d_in[1];
  const float* conv1_k = (const float*)d_in[2];
  const float* conv1_b = (const float*)d_in[3];
  const float* conv2_k = (const float*)d_in[4];
  const float* conv2_b = (const float*)d_in[5];
  const float* conv3_k = (const float*)d_in[6];
  const float* conv3_b = (const float*)d_in[7];
  const float* prim_k  = (const float*)d_in[8];
  const float* prim_b  = (const float*)d_in[9];
  const float* w_route = (const float*)d_in[10];
  const float* d1_w = (const float*)d_in[11];
  const float* d1_b = (const float*)d_in[12];
  const float* d2_w = (const float*)d_in[13];
  const float* d2_b = (const float*)d_in[14];
  const float* d3_w = (const float*)d_in[15];
  const float* d3_b = (const float*)d_in[16];

  // workspace layout (bytes), total 191,021,056 (same as R1-R6 -> proven fits):
  char* ws = (char*)d_ws;
  f16*   h1    = (f16*)(ws + 0);
  f16*   h2    = (f16*)(ws + 42467328);
  f16*   h3    = (f16*)(ws + 93847552);
  float* part  = (float*)(ws + 0);                   // 4 x 9,437,184 B (h1/h2... h1 dead)
  f16*   uhat  = (f16*)(ws + 0);                     // 94,371,840 B (alias, h1-h3 dead)
  float* parts = (float*)(ws + 94371840);            //  2,949,120 B (rest of dead h3)
  float* p     = (float*)(ws + 146276352);           //  9,437,184 B
  float* blog  = (float*)(ws + 155713536);           // 11,796,480 B
  f16*   wd2   = (f16*)(ws + 155713536);             //  4,194,304 B (alias, post-routing)
  f16*   wd3   = (f16*)(ws + 159907840);             //  6,815,744 B (alias, post-routing)
  float* vbuf  = (float*)(ws + 167510016);           //    163,840 B
  f16*   r1h   = (f16*)(ws + 167673856);             //    524,288 B
  f16*   r2h   = (f16*)(ws + 168198144);             //  1,048,576 B
  f16*   wt2   = (f16*)(ws + 170819584);             //  1,327,104 B
  f16*   wt3   = (f16*)(ws + 172146688);             //  5,308,416 B
  f16*   wtp   = (f16*)(ws + 177455104);             // 10,616,832 B
  f16*   wf16  = (f16*)(ws + 188071936);             //  2,949,120 B -> 191,021,056

  float* vout  = (float*)d_out;            // [256,1,10,16] = 40960 f32
  float* recon = (float*)d_out + 40960;    // [256,1600]

  // weight prep
  wtrans_kernel<64, 128><<<dim3(81, 2), 256, 0, stream>>>(conv2_k, wt2);
  wtrans_kernel<128, 256><<<dim3(162, 4), 256, 0, stream>>>(conv3_k, wt3);
  wtrans_kernel<256, 256><<<dim3(324, 4), 256, 0, stream>>>(prim_k, wtp);
  cvtf16_kernel<<<5760, 256, 0, stream>>>(w_route, wf16, 1474560);

  // conv stack
  conv1_kernel<<<10368, 256, 0, stream>>>(x, conv1_k, conv1_b, h1);
  conv_mfma_kernel<36, 36, 64, 28, 28, 128, 1, true, true, 1, true>
      <<<1568, 256, 0, stream>>>(h1, wt2, conv2_b, h2, nullptr);
  // conv3: 8-phase 256^2 (R3 config, best measured)
  conv8p_kernel<28, 28, 128, 20, 20, 256, 1, true, true>
      <<<400, 512, 0, stream>>>(h2, wt3, conv3_b, h3, nullptr);
  // prim caps: K-split x4 (m97 structure), partials + reduce
  conv_mfma_kernel<20, 20, 256, 6, 6, 256, 2, false, false, 4, false>
      <<<576, 256, 0, stream>>>(h3, wtp, prim_b, nullptr, part);
  prim_reduce_kernel<<<9216, 256, 0, stream>>>(part, prim_b, p);

  // fused routing: uhat+partials -> v1 -> [agr/softmax/partial-s] -> v2 -> ... -> v3
  uhatps_kernel<<<2304, 320, 0, stream>>>(wf16, p, uhat, parts);
  sred_kernel<<<256, 160, 0, stream>>>(parts, 0.1f, 18, vbuf, nullptr);
  ba_kernel<true, true><<<2304, 256, 0, stream>>>(uhat, vbuf, blog, parts);
  sred_kernel<<<256, 160, 0, stream>>>(parts, 1.0f, 9, vbuf, nullptr);
  ba_kernel<false, false><<<2304, 256, 0, stream>>>(uhat, vbuf, blog, parts);
  sred_kernel<<<256, 160, 0, stream>>>(parts, 1.0f, 9, vbuf, vout);

  // masked reconstruction (dense weights -> f16 [N][K] into dead blog region)
  wtransg_kernel<<<dim3(16, 32), 256, 0, stream>>>(d2_w, wd2, 1024, 2048, 2048);
  wtransg_kernel<<<dim3(32, 26), 256, 0, stream>>>(d3_w, wd3, 2048, 1600, 1664);
  maskd1_kernel<<<1024, 256, 0, stream>>>(vbuf, y, d1_w, d1_b, r1h);
  gemm_mfma_kernel<1024, 2048, 2048, 0><<<32, 256, 0, stream>>>(r1h, wd2, d2_b, r2h, nullptr);
  gemm_mfma_kernel<2048, 1664, 1600, 1><<<26, 256, 0, stream>>>(r2h, wd3, d3_b, nullptr, recon);
}